// Round 4
// baseline (928.899 us; speedup 1.0000x reference)
//
#include <hip/hip_runtime.h>

#define F_IN 128
#define F_OUT 64
#define ROWS_PER_BLOCK 64

#define NPB 128          // nodes per bucket (128*64*4B = 32 KB LDS accumulator)
#define NPB_SHIFT 7
#define BCAP 800         // max buckets supported by LDS histogram
#define CUR_STRIDE 16    // pad cursors to one 64B line each (atomic contention)
#define CHUNK 512        // edges staged to LDS per round in baccum
#define UNROLL 8         // independent support loads in flight per wave

// ---------------------------------------------------------------------------
// Kernel 1: support = x @ weight   (fp32 vector-ALU GEMM; no fp32 MFMA on CDNA4)
// ---------------------------------------------------------------------------
__global__ __launch_bounds__(256) void gemm_kernel(const float* __restrict__ x,
                                                   const float* __restrict__ w,
                                                   float* __restrict__ support,
                                                   int n_nodes) {
    __shared__ float w_lds[F_IN * F_OUT];                 // 32 KB
    __shared__ float x_lds[ROWS_PER_BLOCK][F_IN + 1];     // ~33 KB

    const int tid = threadIdx.x;

    {
        const float4* w4 = (const float4*)w;
        float4* wl4 = (float4*)w_lds;
        #pragma unroll
        for (int i = tid; i < (F_IN * F_OUT) / 4; i += 256) wl4[i] = w4[i];
    }

    const int row0 = blockIdx.x * ROWS_PER_BLOCK;

    #pragma unroll
    for (int i = tid; i < ROWS_PER_BLOCK * (F_IN / 4); i += 256) {
        const int r   = i >> 5;
        const int k4  = i & 31;
        const int row = row0 + r;
        float4 v = make_float4(0.f, 0.f, 0.f, 0.f);
        if (row < n_nodes) v = ((const float4*)(x + (size_t)row * F_IN))[k4];
        x_lds[r][k4 * 4 + 0] = v.x;
        x_lds[r][k4 * 4 + 1] = v.y;
        x_lds[r][k4 * 4 + 2] = v.z;
        x_lds[r][k4 * 4 + 3] = v.w;
    }
    __syncthreads();

    const int tf = tid & 15;
    const int tr = tid >> 4;

    float acc[4][4] = {};
    #pragma unroll 4
    for (int k = 0; k < F_IN; ++k) {
        const float4 wv = *(const float4*)&w_lds[k * F_OUT + 4 * tf];
        const float x0 = x_lds[4 * tr + 0][k];
        const float x1 = x_lds[4 * tr + 1][k];
        const float x2 = x_lds[4 * tr + 2][k];
        const float x3 = x_lds[4 * tr + 3][k];
        acc[0][0] += x0 * wv.x; acc[0][1] += x0 * wv.y; acc[0][2] += x0 * wv.z; acc[0][3] += x0 * wv.w;
        acc[1][0] += x1 * wv.x; acc[1][1] += x1 * wv.y; acc[1][2] += x1 * wv.z; acc[1][3] += x1 * wv.w;
        acc[2][0] += x2 * wv.x; acc[2][1] += x2 * wv.y; acc[2][2] += x2 * wv.z; acc[2][3] += x2 * wv.w;
        acc[3][0] += x3 * wv.x; acc[3][1] += x3 * wv.y; acc[3][2] += x3 * wv.z; acc[3][3] += x3 * wv.w;
    }

    #pragma unroll
    for (int i = 0; i < 4; ++i) {
        const int row = row0 + 4 * tr + i;
        if (row < n_nodes) {
            float4 v = make_float4(acc[i][0], acc[i][1], acc[i][2], acc[i][3]);
            *(float4*)&support[(size_t)row * F_OUT + 4 * tf] = v;
        }
    }
}

// ---------------------------------------------------------------------------
// Kernel 2: bucket histogram of dst>>7. LDS hist per block, one global
// atomicAdd per (block, nonempty bucket) flush.
// ---------------------------------------------------------------------------
__global__ __launch_bounds__(256) void hist_kernel(const int* __restrict__ edge_dst,
                                                   int* __restrict__ g_hist,
                                                   int n_edges, int nbuckets) {
    __shared__ int h[BCAP];
    for (int i = threadIdx.x; i < BCAP; i += 256) h[i] = 0;
    __syncthreads();

    const int n4 = n_edges >> 2;
    const int4* d4 = (const int4*)edge_dst;
    const int stride = gridDim.x * blockDim.x;
    for (int t = blockIdx.x * blockDim.x + threadIdx.x; t < n4; t += stride) {
        const int4 d = d4[t];
        atomicAdd(&h[d.x >> NPB_SHIFT], 1);
        atomicAdd(&h[d.y >> NPB_SHIFT], 1);
        atomicAdd(&h[d.z >> NPB_SHIFT], 1);
        atomicAdd(&h[d.w >> NPB_SHIFT], 1);
    }
    if (blockIdx.x == 0) {   // tail edges
        for (int e = (n4 << 2) + threadIdx.x; e < n_edges; e += 256)
            atomicAdd(&h[edge_dst[e] >> NPB_SHIFT], 1);
    }
    __syncthreads();
    for (int i = threadIdx.x; i < nbuckets; i += 256)
        if (h[i]) atomicAdd(&g_hist[i], h[i]);
}

// ---------------------------------------------------------------------------
// Kernel 3: single-block exclusive scan of nbuckets (<=1024) counts.
// ---------------------------------------------------------------------------
__global__ __launch_bounds__(256) void scan_kernel(const int* __restrict__ g_hist,
                                                   int* __restrict__ offsets,
                                                   int* __restrict__ cursors,
                                                   int nb) {
    __shared__ int lds[256];
    const int tid = threadIdx.x;
    const int base = tid * 4;

    const int v0 = (base + 0 < nb) ? g_hist[base + 0] : 0;
    const int v1 = (base + 1 < nb) ? g_hist[base + 1] : 0;
    const int v2 = (base + 2 < nb) ? g_hist[base + 2] : 0;
    const int v3 = (base + 3 < nb) ? g_hist[base + 3] : 0;
    const int s1 = v0, s2 = s1 + v1, s3 = s2 + v2, s4 = s3 + v3;

    int t = s4;
    lds[tid] = t;
    __syncthreads();
    #pragma unroll
    for (int off = 1; off < 256; off <<= 1) {
        const int xv = (tid >= off) ? lds[tid - off] : 0;
        __syncthreads();
        t += xv;
        lds[tid] = t;
        __syncthreads();
    }
    const int excl = t - s4;
    const int e0 = excl, e1 = excl + s1, e2 = excl + s2, e3 = excl + s3;
    if (base + 0 < nb) { offsets[base + 0] = e0; cursors[(base + 0) * CUR_STRIDE] = e0; }
    if (base + 1 < nb) { offsets[base + 1] = e1; cursors[(base + 1) * CUR_STRIDE] = e1; }
    if (base + 2 < nb) { offsets[base + 2] = e2; cursors[(base + 2) * CUR_STRIDE] = e2; }
    if (base + 3 < nb) { offsets[base + 3] = e3; cursors[(base + 3) * CUR_STRIDE] = e3; }
    if (tid == 255) offsets[nb] = t;   // grand total = n_edges
}

// ---------------------------------------------------------------------------
// Kernel 4: multisplit scatter into bucket-grouped order.
// sorted[pos].x = src | (dstLocal << 20); sorted[pos].y = val bits.
// Sequential per-bucket allocation -> write frontier ~nb cache lines.
// ---------------------------------------------------------------------------
__global__ __launch_bounds__(256) void bscatter_kernel(const float* __restrict__ edge_val,
                                                       const int* __restrict__ edge_src,
                                                       const int* __restrict__ edge_dst,
                                                       int* __restrict__ cursors,
                                                       int2* __restrict__ sorted,
                                                       int n_edges) {
    const int n4 = n_edges >> 2;
    const int stride = gridDim.x * blockDim.x;
    const int4*   s4 = (const int4*)edge_src;
    const int4*   d4 = (const int4*)edge_dst;
    const float4* v4 = (const float4*)edge_val;

    for (int t = blockIdx.x * blockDim.x + threadIdx.x; t < n4; t += stride) {
        const int4   s = s4[t];
        const int4   d = d4[t];
        const float4 v = v4[t];
        int b, pos;
        b = d.x >> NPB_SHIFT; pos = atomicAdd(&cursors[b * CUR_STRIDE], 1);
        sorted[pos] = make_int2(s.x | ((d.x & (NPB - 1)) << 20), __float_as_int(v.x));
        b = d.y >> NPB_SHIFT; pos = atomicAdd(&cursors[b * CUR_STRIDE], 1);
        sorted[pos] = make_int2(s.y | ((d.y & (NPB - 1)) << 20), __float_as_int(v.y));
        b = d.z >> NPB_SHIFT; pos = atomicAdd(&cursors[b * CUR_STRIDE], 1);
        sorted[pos] = make_int2(s.z | ((d.z & (NPB - 1)) << 20), __float_as_int(v.z));
        b = d.w >> NPB_SHIFT; pos = atomicAdd(&cursors[b * CUR_STRIDE], 1);
        sorted[pos] = make_int2(s.w | ((d.w & (NPB - 1)) << 20), __float_as_int(v.w));
    }
    if (blockIdx.x == 0 && threadIdx.x == 0) {   // tail edges (scalar, <=3)
        for (int e = n4 << 2; e < n_edges; ++e) {
            const int dd = edge_dst[e];
            const int b2 = dd >> NPB_SHIFT;
            const int p2 = atomicAdd(&cursors[b2 * CUR_STRIDE], 1);
            sorted[p2] = make_int2(edge_src[e] | ((dd & (NPB - 1)) << 20),
                                   __float_as_int(edge_val[e]));
        }
    }
}

// ---------------------------------------------------------------------------
// Kernel 5: per-bucket accumulate, restructured for MLP.
//   Phase A: 512 threads stage CHUNK=512 edge records to LDS (coalesced).
//   Phase B: wave w takes slice [w*64, w*64+64); per UNROLL=8 block, issues
//            8 INDEPENDENT support-row loads (indices from LDS) before
//            consuming -> ~8 outstanding 256B loads/wave, 256/CU.
//   LDS fp32 atomics into 128x64 acc (banks f,f+32 -> 2-way = free).
//   ReLU fused; contiguous float4 writeout; no out-zeroing needed.
// ---------------------------------------------------------------------------
__global__ __launch_bounds__(512) void baccum_kernel(const float* __restrict__ support,
                                                     const int2* __restrict__ sorted,
                                                     const int* __restrict__ offsets,
                                                     float* __restrict__ out,
                                                     int n_nodes) {
    __shared__ float acc[NPB * F_OUT];   // 32 KB
    __shared__ int2  ebuf[CHUNK];        // 4 KB
    const int tid = threadIdx.x;
    float4* acc4 = (float4*)acc;
    #pragma unroll
    for (int i = tid; i < NPB * F_OUT / 4; i += 512)
        acc4[i] = make_float4(0.f, 0.f, 0.f, 0.f);

    const int bucket = blockIdx.x;
    const int beg = offsets[bucket];
    const int end = offsets[bucket + 1];
    const int w = tid >> 6;   // wave 0..7
    const int f = tid & 63;   // feature = lane

    for (int cb = beg; cb < end; cb += CHUNK) {
        const int cnt = min(CHUNK, end - cb);
        __syncthreads();                       // acc init done / ebuf free
        for (int i = tid; i < cnt; i += 512) ebuf[i] = sorted[cb + i];
        __syncthreads();

        const int s0 = w * 64;
        const int s1 = min(s0 + 64, cnt);
        int i = s0;
        for (; i + UNROLL <= s1; i += UNROLL) {
            float sv[UNROLL], vals[UNROLL];
            int   rows[UNROLL];
            #pragma unroll
            for (int u = 0; u < UNROLL; ++u) {
                const int2 ev = ebuf[i + u];                 // LDS broadcast
                rows[u] = ((unsigned)ev.x) >> 20;
                vals[u] = __int_as_float(ev.y);
                sv[u] = support[(size_t)(ev.x & 0xFFFFF) * F_OUT + f];
            }
            #pragma unroll
            for (int u = 0; u < UNROLL; ++u)
                atomicAdd(&acc[rows[u] * F_OUT + f], vals[u] * sv[u]);
        }
        for (; i < s1; ++i) {
            const int2 ev = ebuf[i];
            const float sv = support[(size_t)(ev.x & 0xFFFFF) * F_OUT + f];
            atomicAdd(&acc[(((unsigned)ev.x) >> 20) * F_OUT + f],
                      __int_as_float(ev.y) * sv);
        }
    }
    __syncthreads();

    const int base = bucket << NPB_SHIFT;
    const int nrows = min(NPB, n_nodes - base);
    float4* out4 = (float4*)(out + (size_t)base * F_OUT);
    const int lim = nrows * (F_OUT / 4);
    for (int i2 = tid; i2 < lim; i2 += 512) {
        float4 v = acc4[i2];
        v.x = fmaxf(v.x, 0.f); v.y = fmaxf(v.y, 0.f);
        v.z = fmaxf(v.z, 0.f); v.w = fmaxf(v.w, 0.f);
        out4[i2] = v;
    }
}

// ---------------------------------------------------------------------------
// Fallback (ws too small / shapes out of packing range): round-1 atomic path.
// ---------------------------------------------------------------------------
__global__ __launch_bounds__(256) void scatter_kernel(const float* __restrict__ support,
                                                      const float* __restrict__ edge_val,
                                                      const int* __restrict__ edge_src,
                                                      const int* __restrict__ edge_dst,
                                                      float* __restrict__ out,
                                                      int n_edges) {
    const long gid = (long)blockIdx.x * blockDim.x + threadIdx.x;
    const int e = (int)(gid >> 4);
    if (e >= n_edges) return;
    const int fo = (int)(gid & 15) * 4;
    const int src   = edge_src[e];
    const int dst   = edge_dst[e];
    const float val = edge_val[e];
    const float4 s = *(const float4*)&support[(size_t)src * F_OUT + fo];
    float* o = &out[(size_t)dst * F_OUT + fo];
    atomicAdd(o + 0, val * s.x);
    atomicAdd(o + 1, val * s.y);
    atomicAdd(o + 2, val * s.z);
    atomicAdd(o + 3, val * s.w);
}

__global__ __launch_bounds__(256) void relu_kernel(float* __restrict__ out, int n4) {
    const int i = blockIdx.x * blockDim.x + threadIdx.x;
    if (i < n4) {
        float4 v = ((float4*)out)[i];
        v.x = fmaxf(v.x, 0.f); v.y = fmaxf(v.y, 0.f);
        v.z = fmaxf(v.z, 0.f); v.w = fmaxf(v.w, 0.f);
        ((float4*)out)[i] = v;
    }
}

extern "C" void kernel_launch(void* const* d_in, const int* in_sizes, int n_in,
                              void* d_out, int out_size, void* d_ws, size_t ws_size,
                              hipStream_t stream) {
    const float* x        = (const float*)d_in[0];
    const float* w        = (const float*)d_in[1];
    const float* edge_val = (const float*)d_in[2];
    const int*   edge_src = (const int*)d_in[3];
    const int*   edge_dst = (const int*)d_in[4];
    float* out = (float*)d_out;

    const int n_nodes = in_sizes[0] / F_IN;   // 100000
    const int n_edges = in_sizes[2];          // 1600000
    const int nb = (n_nodes + NPB - 1) >> NPB_SHIFT;   // 782 buckets

    char* p = (char*)d_ws;
    float* support = (float*)p;  p += (size_t)n_nodes * F_OUT * sizeof(float);
    int2*  sorted  = (int2*)p;   p += (size_t)n_edges * sizeof(int2);
    int*   offsets = (int*)p;    p += (size_t)(nb + 1) * sizeof(int);
    int*   cursors = (int*)p;    p += (size_t)nb * CUR_STRIDE * sizeof(int);
    int*   g_hist  = (int*)p;    p += (size_t)nb * sizeof(int);
    const size_t ws_needed = (size_t)(p - (char*)d_ws);

    const int gemm_blocks = (n_nodes + ROWS_PER_BLOCK - 1) / ROWS_PER_BLOCK;
    gemm_kernel<<<gemm_blocks, 256, 0, stream>>>(x, w, support, n_nodes);

    const bool ok = (ws_size >= ws_needed) && (nb <= BCAP) && (n_nodes < (1 << 20));
    if (ok) {
        hipMemsetAsync(g_hist, 0, (size_t)nb * sizeof(int), stream);
        hist_kernel<<<256, 256, 0, stream>>>(edge_dst, g_hist, n_edges, nb);
        scan_kernel<<<1, 256, 0, stream>>>(g_hist, offsets, cursors, nb);
        bscatter_kernel<<<1024, 256, 0, stream>>>(edge_val, edge_src, edge_dst,
                                                  cursors, sorted, n_edges);
        baccum_kernel<<<nb, 512, 0, stream>>>(support, sorted, offsets, out, n_nodes);
    } else {
        hipMemsetAsync(d_out, 0, (size_t)out_size * sizeof(float), stream);
        const long st = (long)n_edges * 16;
        scatter_kernel<<<(int)((st + 255) / 256), 256, 0, stream>>>(
            support, edge_val, edge_src, edge_dst, out, n_edges);
        const int n4o = out_size / 4;
        relu_kernel<<<(n4o + 255) / 256, 256, 0, stream>>>(out, n4o);
    }
}

// Round 5
// 314.805 us; speedup vs baseline: 2.9507x; 2.9507x over previous
//
#include <hip/hip_runtime.h>

#define F_IN 128
#define F_OUT 64
#define ROWS_PER_BLOCK 64

#define NPB 128          // nodes per bucket
#define NPB_SHIFT 7
#define BCAP 800         // max buckets supported by LDS histogram
#define CUR_STRIDE 16    // pad global cursors to one 64B line each
#define ECAP 2560        // edges staged/sorted per LDS chunk (mean 2046, +11 sigma)

// ---------------------------------------------------------------------------
// Kernel 1: support = x @ weight   (fp32 vector-ALU GEMM; no fp32 MFMA on CDNA4)
// ---------------------------------------------------------------------------
__global__ __launch_bounds__(256) void gemm_kernel(const float* __restrict__ x,
                                                   const float* __restrict__ w,
                                                   float* __restrict__ support,
                                                   int n_nodes) {
    __shared__ float w_lds[F_IN * F_OUT];                 // 32 KB
    __shared__ float x_lds[ROWS_PER_BLOCK][F_IN + 1];     // ~33 KB

    const int tid = threadIdx.x;

    {
        const float4* w4 = (const float4*)w;
        float4* wl4 = (float4*)w_lds;
        #pragma unroll
        for (int i = tid; i < (F_IN * F_OUT) / 4; i += 256) wl4[i] = w4[i];
    }

    const int row0 = blockIdx.x * ROWS_PER_BLOCK;

    #pragma unroll
    for (int i = tid; i < ROWS_PER_BLOCK * (F_IN / 4); i += 256) {
        const int r   = i >> 5;
        const int k4  = i & 31;
        const int row = row0 + r;
        float4 v = make_float4(0.f, 0.f, 0.f, 0.f);
        if (row < n_nodes) v = ((const float4*)(x + (size_t)row * F_IN))[k4];
        x_lds[r][k4 * 4 + 0] = v.x;
        x_lds[r][k4 * 4 + 1] = v.y;
        x_lds[r][k4 * 4 + 2] = v.z;
        x_lds[r][k4 * 4 + 3] = v.w;
    }
    __syncthreads();

    const int tf = tid & 15;
    const int tr = tid >> 4;

    float acc[4][4] = {};
    #pragma unroll 4
    for (int k = 0; k < F_IN; ++k) {
        const float4 wv = *(const float4*)&w_lds[k * F_OUT + 4 * tf];
        const float x0 = x_lds[4 * tr + 0][k];
        const float x1 = x_lds[4 * tr + 1][k];
        const float x2 = x_lds[4 * tr + 2][k];
        const float x3 = x_lds[4 * tr + 3][k];
        acc[0][0] += x0 * wv.x; acc[0][1] += x0 * wv.y; acc[0][2] += x0 * wv.z; acc[0][3] += x0 * wv.w;
        acc[1][0] += x1 * wv.x; acc[1][1] += x1 * wv.y; acc[1][2] += x1 * wv.z; acc[1][3] += x1 * wv.w;
        acc[2][0] += x2 * wv.x; acc[2][1] += x2 * wv.y; acc[2][2] += x2 * wv.z; acc[2][3] += x2 * wv.w;
        acc[3][0] += x3 * wv.x; acc[3][1] += x3 * wv.y; acc[3][2] += x3 * wv.z; acc[3][3] += x3 * wv.w;
    }

    #pragma unroll
    for (int i = 0; i < 4; ++i) {
        const int row = row0 + 4 * tr + i;
        if (row < n_nodes) {
            float4 v = make_float4(acc[i][0], acc[i][1], acc[i][2], acc[i][3]);
            *(float4*)&support[(size_t)row * F_OUT + 4 * tf] = v;
        }
    }
}

// ---------------------------------------------------------------------------
// Kernel 2: bucket histogram of dst>>7 (LDS hist, one global add per bin).
// ---------------------------------------------------------------------------
__global__ __launch_bounds__(256) void hist_kernel(const int* __restrict__ edge_dst,
                                                   int* __restrict__ g_hist,
                                                   int n_edges, int nbuckets) {
    __shared__ int h[BCAP];
    for (int i = threadIdx.x; i < BCAP; i += 256) h[i] = 0;
    __syncthreads();

    const int n4 = n_edges >> 2;
    const int4* d4 = (const int4*)edge_dst;
    const int stride = gridDim.x * blockDim.x;
    for (int t = blockIdx.x * blockDim.x + threadIdx.x; t < n4; t += stride) {
        const int4 d = d4[t];
        atomicAdd(&h[d.x >> NPB_SHIFT], 1);
        atomicAdd(&h[d.y >> NPB_SHIFT], 1);
        atomicAdd(&h[d.z >> NPB_SHIFT], 1);
        atomicAdd(&h[d.w >> NPB_SHIFT], 1);
    }
    if (blockIdx.x == 0) {   // tail edges
        for (int e = (n4 << 2) + threadIdx.x; e < n_edges; e += 256)
            atomicAdd(&h[edge_dst[e] >> NPB_SHIFT], 1);
    }
    __syncthreads();
    for (int i = threadIdx.x; i < nbuckets; i += 256)
        if (h[i]) atomicAdd(&g_hist[i], h[i]);
}

// ---------------------------------------------------------------------------
// Kernel 3: single-block exclusive scan of nbuckets (<=1024) counts.
// ---------------------------------------------------------------------------
__global__ __launch_bounds__(256) void scan_kernel(const int* __restrict__ g_hist,
                                                   int* __restrict__ offsets,
                                                   int* __restrict__ cursors,
                                                   int nb) {
    __shared__ int lds[256];
    const int tid = threadIdx.x;
    const int base = tid * 4;

    const int v0 = (base + 0 < nb) ? g_hist[base + 0] : 0;
    const int v1 = (base + 1 < nb) ? g_hist[base + 1] : 0;
    const int v2 = (base + 2 < nb) ? g_hist[base + 2] : 0;
    const int v3 = (base + 3 < nb) ? g_hist[base + 3] : 0;
    const int s1 = v0, s2 = s1 + v1, s3 = s2 + v2, s4 = s3 + v3;

    int t = s4;
    lds[tid] = t;
    __syncthreads();
    #pragma unroll
    for (int off = 1; off < 256; off <<= 1) {
        const int xv = (tid >= off) ? lds[tid - off] : 0;
        __syncthreads();
        t += xv;
        lds[tid] = t;
        __syncthreads();
    }
    const int excl = t - s4;
    const int e0 = excl, e1 = excl + s1, e2 = excl + s2, e3 = excl + s3;
    if (base + 0 < nb) { offsets[base + 0] = e0; cursors[(base + 0) * CUR_STRIDE] = e0; }
    if (base + 1 < nb) { offsets[base + 1] = e1; cursors[(base + 1) * CUR_STRIDE] = e1; }
    if (base + 2 < nb) { offsets[base + 2] = e2; cursors[(base + 2) * CUR_STRIDE] = e2; }
    if (base + 3 < nb) { offsets[base + 3] = e3; cursors[(base + 3) * CUR_STRIDE] = e3; }
    if (tid == 255) offsets[nb] = t;   // grand total = n_edges
}

// ---------------------------------------------------------------------------
// Kernel 4: multisplit scatter into bucket-grouped order.
// sorted[pos].x = src | (dstLocal << 20); sorted[pos].y = val bits.
// ---------------------------------------------------------------------------
__global__ __launch_bounds__(256) void bscatter_kernel(const float* __restrict__ edge_val,
                                                       const int* __restrict__ edge_src,
                                                       const int* __restrict__ edge_dst,
                                                       int* __restrict__ cursors,
                                                       int2* __restrict__ sorted,
                                                       int n_edges) {
    const int n4 = n_edges >> 2;
    const int stride = gridDim.x * blockDim.x;
    const int4*   s4 = (const int4*)edge_src;
    const int4*   d4 = (const int4*)edge_dst;
    const float4* v4 = (const float4*)edge_val;

    for (int t = blockIdx.x * blockDim.x + threadIdx.x; t < n4; t += stride) {
        const int4   s = s4[t];
        const int4   d = d4[t];
        const float4 v = v4[t];
        int b, pos;
        b = d.x >> NPB_SHIFT; pos = atomicAdd(&cursors[b * CUR_STRIDE], 1);
        sorted[pos] = make_int2(s.x | ((d.x & (NPB - 1)) << 20), __float_as_int(v.x));
        b = d.y >> NPB_SHIFT; pos = atomicAdd(&cursors[b * CUR_STRIDE], 1);
        sorted[pos] = make_int2(s.y | ((d.y & (NPB - 1)) << 20), __float_as_int(v.y));
        b = d.z >> NPB_SHIFT; pos = atomicAdd(&cursors[b * CUR_STRIDE], 1);
        sorted[pos] = make_int2(s.z | ((d.z & (NPB - 1)) << 20), __float_as_int(v.z));
        b = d.w >> NPB_SHIFT; pos = atomicAdd(&cursors[b * CUR_STRIDE], 1);
        sorted[pos] = make_int2(s.w | ((d.w & (NPB - 1)) << 20), __float_as_int(v.w));
    }
    if (blockIdx.x == 0 && threadIdx.x == 0) {   // tail edges (scalar, <=3)
        for (int e = n4 << 2; e < n_edges; ++e) {
            const int dd = edge_dst[e];
            const int b2 = dd >> NPB_SHIFT;
            const int p2 = atomicAdd(&cursors[b2 * CUR_STRIDE], 1);
            sorted[p2] = make_int2(edge_src[e] | ((dd & (NPB - 1)) << 20),
                                   __float_as_int(edge_val[e]));
        }
    }
}

// ---------------------------------------------------------------------------
// Kernel 5 (v2): per-bucket counting sort in LDS + per-node REGISTER gather.
//   Chunk (<=ECAP edges): stage to LDS + 128-bin hist; scan; permute (ushort).
//   Gather: group = 16 lanes owns node g+32j (j=0..3); per edge one float4
//   support load (256 B/group, coalesced), indices from LDS -> 4-wide
//   independent load batches; accumulate in REGISTERS (no LDS atomics).
//   ReLU fused; 256 B contiguous float4 stores. Chunking keeps reg acc live.
// ---------------------------------------------------------------------------
__global__ __launch_bounds__(512) void baccum_kernel(const float* __restrict__ support,
                                                     const int2* __restrict__ sorted,
                                                     const int* __restrict__ offsets,
                                                     float* __restrict__ out,
                                                     int n_nodes) {
    __shared__ int2 ebuf[ECAP];                    // 20 KB
    __shared__ unsigned short order[ECAP];         // 5 KB
    __shared__ int hist[NPB];
    __shared__ int scanbuf[NPB];
    __shared__ int node_off[NPB + 1];
    __shared__ int cursor[NPB];

    const int tid = threadIdx.x;
    const int bucket = blockIdx.x;
    const int beg = offsets[bucket];
    const int end = offsets[bucket + 1];

    const int g  = tid >> 4;        // group 0..31
    const int f4 = tid & 15;        // float4 feature index 0..15
    const float4* sup4 = (const float4*)support;

    float4 acc[4];
    #pragma unroll
    for (int j = 0; j < 4; ++j) acc[j] = make_float4(0.f, 0.f, 0.f, 0.f);

    for (int cb = beg; cb < end; cb += ECAP) {
        const int cnt = min(ECAP, end - cb);

        __syncthreads();                        // prev gather done / ebuf free
        if (tid < NPB) hist[tid] = 0;
        __syncthreads();

        // Stage + histogram.
        for (int i = tid; i < cnt; i += 512) {
            const int2 ev = sorted[cb + i];
            ebuf[i] = ev;
            atomicAdd(&hist[((unsigned)ev.x) >> 20], 1);
        }
        __syncthreads();

        // Inclusive scan of 128 bins (Hillis-Steele, block-wide barriers).
        if (tid < NPB) scanbuf[tid] = hist[tid];
        __syncthreads();
        #pragma unroll
        for (int off = 1; off < NPB; off <<= 1) {
            int v = 0;
            if (tid < NPB && tid >= off) v = scanbuf[tid - off];
            __syncthreads();
            if (tid < NPB) scanbuf[tid] += v;
            __syncthreads();
        }
        if (tid < NPB) {
            node_off[tid + 1] = scanbuf[tid];
            cursor[tid] = scanbuf[tid] - hist[tid];   // exclusive start
            if (tid == 0) node_off[0] = 0;
        }
        __syncthreads();

        // Permutation: order[rank] = edge index within chunk.
        for (int i = tid; i < cnt; i += 512) {
            const int dl = ((unsigned)ebuf[i].x) >> 20;
            const int r = atomicAdd(&cursor[dl], 1);
            order[r] = (unsigned short)i;
        }
        __syncthreads();

        // Register gather: node j of this group = local node g + 32*j.
        #pragma unroll
        for (int j = 0; j < 4; ++j) {
            const int nl = g + 32 * j;
            int k = node_off[nl];
            const int ke = node_off[nl + 1];
            float4 a = acc[j];
            while (k + 4 <= ke) {
                int2 e0 = ebuf[order[k + 0]];
                int2 e1 = ebuf[order[k + 1]];
                int2 e2 = ebuf[order[k + 2]];
                int2 e3 = ebuf[order[k + 3]];
                const float4 s0 = sup4[(size_t)(e0.x & 0xFFFFF) * 16 + f4];
                const float4 s1 = sup4[(size_t)(e1.x & 0xFFFFF) * 16 + f4];
                const float4 s2 = sup4[(size_t)(e2.x & 0xFFFFF) * 16 + f4];
                const float4 s3 = sup4[(size_t)(e3.x & 0xFFFFF) * 16 + f4];
                const float v0 = __int_as_float(e0.y);
                const float v1 = __int_as_float(e1.y);
                const float v2 = __int_as_float(e2.y);
                const float v3 = __int_as_float(e3.y);
                a.x += v0 * s0.x; a.y += v0 * s0.y; a.z += v0 * s0.z; a.w += v0 * s0.w;
                a.x += v1 * s1.x; a.y += v1 * s1.y; a.z += v1 * s1.z; a.w += v1 * s1.w;
                a.x += v2 * s2.x; a.y += v2 * s2.y; a.z += v2 * s2.z; a.w += v2 * s2.w;
                a.x += v3 * s3.x; a.y += v3 * s3.y; a.z += v3 * s3.z; a.w += v3 * s3.w;
                k += 4;
            }
            for (; k < ke; ++k) {
                const int2 e0 = ebuf[order[k]];
                const float4 s0 = sup4[(size_t)(e0.x & 0xFFFFF) * 16 + f4];
                const float v0 = __int_as_float(e0.y);
                a.x += v0 * s0.x; a.y += v0 * s0.y; a.z += v0 * s0.z; a.w += v0 * s0.w;
            }
            acc[j] = a;
        }
    }

    // Writeout (also for empty buckets: zeros, ReLU(0)=0 matches segment_sum).
    const int base = bucket << NPB_SHIFT;
    #pragma unroll
    for (int j = 0; j < 4; ++j) {
        const int node = base + g + 32 * j;
        if (node < n_nodes) {
            float4 v = acc[j];
            v.x = fmaxf(v.x, 0.f); v.y = fmaxf(v.y, 0.f);
            v.z = fmaxf(v.z, 0.f); v.w = fmaxf(v.w, 0.f);
            ((float4*)out)[(size_t)node * 16 + f4] = v;
        }
    }
}

// ---------------------------------------------------------------------------
// Fallback (ws too small / shapes out of packing range): round-1 atomic path.
// ---------------------------------------------------------------------------
__global__ __launch_bounds__(256) void scatter_kernel(const float* __restrict__ support,
                                                      const float* __restrict__ edge_val,
                                                      const int* __restrict__ edge_src,
                                                      const int* __restrict__ edge_dst,
                                                      float* __restrict__ out,
                                                      int n_edges) {
    const long gid = (long)blockIdx.x * blockDim.x + threadIdx.x;
    const int e = (int)(gid >> 4);
    if (e >= n_edges) return;
    const int fo = (int)(gid & 15) * 4;
    const int src   = edge_src[e];
    const int dst   = edge_dst[e];
    const float val = edge_val[e];
    const float4 s = *(const float4*)&support[(size_t)src * F_OUT + fo];
    float* o = &out[(size_t)dst * F_OUT + fo];
    atomicAdd(o + 0, val * s.x);
    atomicAdd(o + 1, val * s.y);
    atomicAdd(o + 2, val * s.z);
    atomicAdd(o + 3, val * s.w);
}

__global__ __launch_bounds__(256) void relu_kernel(float* __restrict__ out, int n4) {
    const int i = blockIdx.x * blockDim.x + threadIdx.x;
    if (i < n4) {
        float4 v = ((float4*)out)[i];
        v.x = fmaxf(v.x, 0.f); v.y = fmaxf(v.y, 0.f);
        v.z = fmaxf(v.z, 0.f); v.w = fmaxf(v.w, 0.f);
        ((float4*)out)[i] = v;
    }
}

extern "C" void kernel_launch(void* const* d_in, const int* in_sizes, int n_in,
                              void* d_out, int out_size, void* d_ws, size_t ws_size,
                              hipStream_t stream) {
    const float* x        = (const float*)d_in[0];
    const float* w        = (const float*)d_in[1];
    const float* edge_val = (const float*)d_in[2];
    const int*   edge_src = (const int*)d_in[3];
    const int*   edge_dst = (const int*)d_in[4];
    float* out = (float*)d_out;

    const int n_nodes = in_sizes[0] / F_IN;   // 100000
    const int n_edges = in_sizes[2];          // 1600000
    const int nb = (n_nodes + NPB - 1) >> NPB_SHIFT;   // 782 buckets

    char* p = (char*)d_ws;
    float* support = (float*)p;  p += (size_t)n_nodes * F_OUT * sizeof(float);
    int2*  sorted  = (int2*)p;   p += (size_t)n_edges * sizeof(int2);
    int*   offsets = (int*)p;    p += (size_t)(nb + 1) * sizeof(int);
    int*   cursors = (int*)p;    p += (size_t)nb * CUR_STRIDE * sizeof(int);
    int*   g_hist  = (int*)p;    p += (size_t)nb * sizeof(int);
    const size_t ws_needed = (size_t)(p - (char*)d_ws);

    const int gemm_blocks = (n_nodes + ROWS_PER_BLOCK - 1) / ROWS_PER_BLOCK;
    gemm_kernel<<<gemm_blocks, 256, 0, stream>>>(x, w, support, n_nodes);

    const bool ok = (ws_size >= ws_needed) && (nb <= BCAP) && (n_nodes < (1 << 20));
    if (ok) {
        hipMemsetAsync(g_hist, 0, (size_t)nb * sizeof(int), stream);
        hist_kernel<<<256, 256, 0, stream>>>(edge_dst, g_hist, n_edges, nb);
        scan_kernel<<<1, 256, 0, stream>>>(g_hist, offsets, cursors, nb);
        bscatter_kernel<<<1024, 256, 0, stream>>>(edge_val, edge_src, edge_dst,
                                                  cursors, sorted, n_edges);
        baccum_kernel<<<nb, 512, 0, stream>>>(support, sorted, offsets, out, n_nodes);
    } else {
        hipMemsetAsync(d_out, 0, (size_t)out_size * sizeof(float), stream);
        const long st = (long)n_edges * 16;
        scatter_kernel<<<(int)((st + 255) / 256), 256, 0, stream>>>(
            support, edge_val, edge_src, edge_dst, out, n_edges);
        const int n4o = out_size / 4;
        relu_kernel<<<(n4o + 255) / 256, 256, 0, stream>>>(out, n4o);
    }
}

// Round 6
// 308.452 us; speedup vs baseline: 3.0115x; 1.0206x over previous
//
#include <hip/hip_runtime.h>

#define F_IN 128
#define F_OUT 64
#define ROWS_PER_BLOCK 64

#define NPB 128          // nodes per bucket
#define NPB_SHIFT 7
#define BCAP 800         // max buckets supported by LDS histogram
#define NPART 8          // XCD partitions (blockIdx&7 round-robin heuristic)
#define CUR_STRIDE 16    // pad global cursors to one 64B line each
#define ECAP 2560        // edges staged/sorted per LDS chunk in baccum

// Partition of an edge: constant per 1024-edge group. For a grid-stride loop
// over int4 tiles with 256 threads and gridDim%8==0, (e>>10)&7 == blockIdx&7.
#define EDGE_PART(e) (((e) >> 10) & (NPART - 1))

// ---------------------------------------------------------------------------
// Kernel 1: support = x @ weight   (fp32 vector-ALU GEMM; no fp32 MFMA on CDNA4)
// ---------------------------------------------------------------------------
__global__ __launch_bounds__(256) void gemm_kernel(const float* __restrict__ x,
                                                   const float* __restrict__ w,
                                                   float* __restrict__ support,
                                                   int n_nodes) {
    __shared__ float w_lds[F_IN * F_OUT];                 // 32 KB
    __shared__ float x_lds[ROWS_PER_BLOCK][F_IN + 1];     // ~33 KB

    const int tid = threadIdx.x;

    {
        const float4* w4 = (const float4*)w;
        float4* wl4 = (float4*)w_lds;
        #pragma unroll
        for (int i = tid; i < (F_IN * F_OUT) / 4; i += 256) wl4[i] = w4[i];
    }

    const int row0 = blockIdx.x * ROWS_PER_BLOCK;

    #pragma unroll
    for (int i = tid; i < ROWS_PER_BLOCK * (F_IN / 4); i += 256) {
        const int r   = i >> 5;
        const int k4  = i & 31;
        const int row = row0 + r;
        float4 v = make_float4(0.f, 0.f, 0.f, 0.f);
        if (row < n_nodes) v = ((const float4*)(x + (size_t)row * F_IN))[k4];
        x_lds[r][k4 * 4 + 0] = v.x;
        x_lds[r][k4 * 4 + 1] = v.y;
        x_lds[r][k4 * 4 + 2] = v.z;
        x_lds[r][k4 * 4 + 3] = v.w;
    }
    __syncthreads();

    const int tf = tid & 15;
    const int tr = tid >> 4;

    float acc[4][4] = {};
    #pragma unroll 4
    for (int k = 0; k < F_IN; ++k) {
        const float4 wv = *(const float4*)&w_lds[k * F_OUT + 4 * tf];
        const float x0 = x_lds[4 * tr + 0][k];
        const float x1 = x_lds[4 * tr + 1][k];
        const float x2 = x_lds[4 * tr + 2][k];
        const float x3 = x_lds[4 * tr + 3][k];
        acc[0][0] += x0 * wv.x; acc[0][1] += x0 * wv.y; acc[0][2] += x0 * wv.z; acc[0][3] += x0 * wv.w;
        acc[1][0] += x1 * wv.x; acc[1][1] += x1 * wv.y; acc[1][2] += x1 * wv.z; acc[1][3] += x1 * wv.w;
        acc[2][0] += x2 * wv.x; acc[2][1] += x2 * wv.y; acc[2][2] += x2 * wv.z; acc[2][3] += x2 * wv.w;
        acc[3][0] += x3 * wv.x; acc[3][1] += x3 * wv.y; acc[3][2] += x3 * wv.z; acc[3][3] += x3 * wv.w;
    }

    #pragma unroll
    for (int i = 0; i < 4; ++i) {
        const int row = row0 + 4 * tr + i;
        if (row < n_nodes) {
            float4 v = make_float4(acc[i][0], acc[i][1], acc[i][2], acc[i][3]);
            *(float4*)&support[(size_t)row * F_OUT + 4 * tf] = v;
        }
    }
}

// ---------------------------------------------------------------------------
// Kernel 2: per-(bucket, partition) histogram. A block's tiles all satisfy
// (t>>8)&7 == blockIdx&7 (grid%8==0, 256 thr), so its LDS hist belongs to a
// single partition -> flush to g_hist[b*8 + (blockIdx&7)].
// ---------------------------------------------------------------------------
__global__ __launch_bounds__(256) void hist_kernel(const int* __restrict__ edge_dst,
                                                   int* __restrict__ g_hist,
                                                   int n_edges, int nbuckets) {
    __shared__ int h[BCAP];
    for (int i = threadIdx.x; i < BCAP; i += 256) h[i] = 0;
    __syncthreads();

    const int n4 = n_edges >> 2;
    const int4* d4 = (const int4*)edge_dst;
    const int stride = gridDim.x * blockDim.x;
    for (int t = blockIdx.x * blockDim.x + threadIdx.x; t < n4; t += stride) {
        const int4 d = d4[t];
        atomicAdd(&h[d.x >> NPB_SHIFT], 1);
        atomicAdd(&h[d.y >> NPB_SHIFT], 1);
        atomicAdd(&h[d.z >> NPB_SHIFT], 1);
        atomicAdd(&h[d.w >> NPB_SHIFT], 1);
    }
    if (blockIdx.x == 0) {   // tail edges: direct global add with formula part
        for (int e = (n4 << 2) + threadIdx.x; e < n_edges; e += 256)
            atomicAdd(&g_hist[(edge_dst[e] >> NPB_SHIFT) * NPART + EDGE_PART(e)], 1);
    }
    __syncthreads();
    const int p = blockIdx.x & (NPART - 1);
    for (int i = threadIdx.x; i < nbuckets; i += 256)
        if (h[i]) atomicAdd(&g_hist[i * NPART + p], h[i]);
}

// ---------------------------------------------------------------------------
// Kernel 3: single-block exclusive scan of S = nb*8 segment counts
// (multi-tile with carry). Writes offsets[0..S] and padded cursors.
// ---------------------------------------------------------------------------
__global__ __launch_bounds__(256) void scan_kernel(const int* __restrict__ g_hist,
                                                   int* __restrict__ offsets,
                                                   int* __restrict__ cursors,
                                                   int S) {
    __shared__ int lds[256];
    __shared__ int carry_s;
    const int tid = threadIdx.x;
    if (tid == 0) carry_s = 0;
    __syncthreads();

    const int ntiles = (S + 1023) >> 10;
    for (int tile = 0; tile < ntiles; ++tile) {
        const int base = (tile << 10) + tid * 4;
        const int v0 = (base + 0 < S) ? g_hist[base + 0] : 0;
        const int v1 = (base + 1 < S) ? g_hist[base + 1] : 0;
        const int v2 = (base + 2 < S) ? g_hist[base + 2] : 0;
        const int v3 = (base + 3 < S) ? g_hist[base + 3] : 0;
        const int s1 = v0, s2 = s1 + v1, s3 = s2 + v2, s4 = s3 + v3;

        int t = s4;
        lds[tid] = t;
        __syncthreads();
        #pragma unroll
        for (int off = 1; off < 256; off <<= 1) {
            const int xv = (tid >= off) ? lds[tid - off] : 0;
            __syncthreads();
            t += xv;
            lds[tid] = t;
            __syncthreads();
        }
        const int carry = carry_s;   // stable: last write was barrier-protected
        const int excl = t - s4 + carry;
        const int e0 = excl, e1 = excl + s1, e2 = excl + s2, e3 = excl + s3;
        if (base + 0 < S) { offsets[base + 0] = e0; cursors[(base + 0) * CUR_STRIDE] = e0; }
        if (base + 1 < S) { offsets[base + 1] = e1; cursors[(base + 1) * CUR_STRIDE] = e1; }
        if (base + 2 < S) { offsets[base + 2] = e2; cursors[(base + 2) * CUR_STRIDE] = e2; }
        if (base + 3 < S) { offsets[base + 3] = e3; cursors[(base + 3) * CUR_STRIDE] = e3; }
        __syncthreads();             // everyone has read carry_s
        if (tid == 255) carry_s = carry + t;
        __syncthreads();
    }
    if (tid == 0) offsets[S] = carry_s;   // grand total = n_edges
}

// ---------------------------------------------------------------------------
// Kernel 4: multisplit scatter into (bucket, partition) segments.
// sorted[pos].x = src | (dstLocal << 20); sorted[pos].y = val bits.
// Writers of segment (b, blockIdx&7) all share blockIdx&7 -> same XCD under
// round-robin dispatch -> 64B lines fill within one L2 (no write amp).
// ---------------------------------------------------------------------------
__global__ __launch_bounds__(256) void bscatter_kernel(const float* __restrict__ edge_val,
                                                       const int* __restrict__ edge_src,
                                                       const int* __restrict__ edge_dst,
                                                       int* __restrict__ cursors,
                                                       int2* __restrict__ sorted,
                                                       int n_edges) {
    const int n4 = n_edges >> 2;
    const int stride = gridDim.x * blockDim.x;
    const int4*   s4 = (const int4*)edge_src;
    const int4*   d4 = (const int4*)edge_dst;
    const float4* v4 = (const float4*)edge_val;
    const int p = blockIdx.x & (NPART - 1);

    for (int t = blockIdx.x * blockDim.x + threadIdx.x; t < n4; t += stride) {
        const int4   s = s4[t];
        const int4   d = d4[t];
        const float4 v = v4[t];
        int sid, pos;
        sid = (d.x >> NPB_SHIFT) * NPART + p; pos = atomicAdd(&cursors[sid * CUR_STRIDE], 1);
        sorted[pos] = make_int2(s.x | ((d.x & (NPB - 1)) << 20), __float_as_int(v.x));
        sid = (d.y >> NPB_SHIFT) * NPART + p; pos = atomicAdd(&cursors[sid * CUR_STRIDE], 1);
        sorted[pos] = make_int2(s.y | ((d.y & (NPB - 1)) << 20), __float_as_int(v.y));
        sid = (d.z >> NPB_SHIFT) * NPART + p; pos = atomicAdd(&cursors[sid * CUR_STRIDE], 1);
        sorted[pos] = make_int2(s.z | ((d.z & (NPB - 1)) << 20), __float_as_int(v.z));
        sid = (d.w >> NPB_SHIFT) * NPART + p; pos = atomicAdd(&cursors[sid * CUR_STRIDE], 1);
        sorted[pos] = make_int2(s.w | ((d.w & (NPB - 1)) << 20), __float_as_int(v.w));
    }
    if (blockIdx.x == 0 && threadIdx.x == 0) {   // tail edges (scalar, <=3)
        for (int e = n4 << 2; e < n_edges; ++e) {
            const int dd = edge_dst[e];
            const int sid2 = (dd >> NPB_SHIFT) * NPART + EDGE_PART(e);
            const int p2 = atomicAdd(&cursors[sid2 * CUR_STRIDE], 1);
            sorted[p2] = make_int2(edge_src[e] | ((dd & (NPB - 1)) << 20),
                                   __float_as_int(edge_val[e]));
        }
    }
}

// ---------------------------------------------------------------------------
// Kernel 5: per-bucket counting sort in LDS + per-node REGISTER gather.
// Bucket b's 8 segments are contiguous: [offsets[8b], offsets[8b+8]).
// ---------------------------------------------------------------------------
__global__ __launch_bounds__(512) void baccum_kernel(const float* __restrict__ support,
                                                     const int2* __restrict__ sorted,
                                                     const int* __restrict__ offsets,
                                                     float* __restrict__ out,
                                                     int n_nodes) {
    __shared__ int2 ebuf[ECAP];                    // 20 KB
    __shared__ unsigned short order[ECAP];         // 5 KB
    __shared__ int hist[NPB];
    __shared__ int scanbuf[NPB];
    __shared__ int node_off[NPB + 1];
    __shared__ int cursor[NPB];

    const int tid = threadIdx.x;
    const int bucket = blockIdx.x;
    const int beg = offsets[bucket * NPART];
    const int end = offsets[bucket * NPART + NPART];

    const int g  = tid >> 4;        // group 0..31
    const int f4 = tid & 15;        // float4 feature index 0..15
    const float4* sup4 = (const float4*)support;

    float4 acc[4];
    #pragma unroll
    for (int j = 0; j < 4; ++j) acc[j] = make_float4(0.f, 0.f, 0.f, 0.f);

    for (int cb = beg; cb < end; cb += ECAP) {
        const int cnt = min(ECAP, end - cb);

        __syncthreads();                        // prev gather done / ebuf free
        if (tid < NPB) hist[tid] = 0;
        __syncthreads();

        // Stage + histogram.
        for (int i = tid; i < cnt; i += 512) {
            const int2 ev = sorted[cb + i];
            ebuf[i] = ev;
            atomicAdd(&hist[((unsigned)ev.x) >> 20], 1);
        }
        __syncthreads();

        // Inclusive scan of 128 bins.
        if (tid < NPB) scanbuf[tid] = hist[tid];
        __syncthreads();
        #pragma unroll
        for (int off = 1; off < NPB; off <<= 1) {
            int v = 0;
            if (tid < NPB && tid >= off) v = scanbuf[tid - off];
            __syncthreads();
            if (tid < NPB) scanbuf[tid] += v;
            __syncthreads();
        }
        if (tid < NPB) {
            node_off[tid + 1] = scanbuf[tid];
            cursor[tid] = scanbuf[tid] - hist[tid];   // exclusive start
            if (tid == 0) node_off[0] = 0;
        }
        __syncthreads();

        // Permutation: order[rank] = edge index within chunk.
        for (int i = tid; i < cnt; i += 512) {
            const int dl = ((unsigned)ebuf[i].x) >> 20;
            const int r = atomicAdd(&cursor[dl], 1);
            order[r] = (unsigned short)i;
        }
        __syncthreads();

        // Register gather: node j of this group = local node g + 32*j.
        #pragma unroll
        for (int j = 0; j < 4; ++j) {
            const int nl = g + 32 * j;
            int k = node_off[nl];
            const int ke = node_off[nl + 1];
            float4 a = acc[j];
            while (k + 4 <= ke) {
                int2 e0 = ebuf[order[k + 0]];
                int2 e1 = ebuf[order[k + 1]];
                int2 e2 = ebuf[order[k + 2]];
                int2 e3 = ebuf[order[k + 3]];
                const float4 s0 = sup4[(size_t)(e0.x & 0xFFFFF) * 16 + f4];
                const float4 s1 = sup4[(size_t)(e1.x & 0xFFFFF) * 16 + f4];
                const float4 s2 = sup4[(size_t)(e2.x & 0xFFFFF) * 16 + f4];
                const float4 s3 = sup4[(size_t)(e3.x & 0xFFFFF) * 16 + f4];
                const float v0 = __int_as_float(e0.y);
                const float v1 = __int_as_float(e1.y);
                const float v2 = __int_as_float(e2.y);
                const float v3 = __int_as_float(e3.y);
                a.x += v0 * s0.x; a.y += v0 * s0.y; a.z += v0 * s0.z; a.w += v0 * s0.w;
                a.x += v1 * s1.x; a.y += v1 * s1.y; a.z += v1 * s1.z; a.w += v1 * s1.w;
                a.x += v2 * s2.x; a.y += v2 * s2.y; a.z += v2 * s2.z; a.w += v2 * s2.w;
                a.x += v3 * s3.x; a.y += v3 * s3.y; a.z += v3 * s3.z; a.w += v3 * s3.w;
                k += 4;
            }
            for (; k < ke; ++k) {
                const int2 e0 = ebuf[order[k]];
                const float4 s0 = sup4[(size_t)(e0.x & 0xFFFFF) * 16 + f4];
                const float v0 = __int_as_float(e0.y);
                a.x += v0 * s0.x; a.y += v0 * s0.y; a.z += v0 * s0.z; a.w += v0 * s0.w;
            }
            acc[j] = a;
        }
    }

    // Writeout (also for empty buckets: zeros, ReLU(0)=0 matches segment_sum).
    const int base = bucket << NPB_SHIFT;
    #pragma unroll
    for (int j = 0; j < 4; ++j) {
        const int node = base + g + 32 * j;
        if (node < n_nodes) {
            float4 v = acc[j];
            v.x = fmaxf(v.x, 0.f); v.y = fmaxf(v.y, 0.f);
            v.z = fmaxf(v.z, 0.f); v.w = fmaxf(v.w, 0.f);
            ((float4*)out)[(size_t)node * 16 + f4] = v;
        }
    }
}

// ---------------------------------------------------------------------------
// Fallback (ws too small / shapes out of packing range): round-1 atomic path.
// ---------------------------------------------------------------------------
__global__ __launch_bounds__(256) void scatter_kernel(const float* __restrict__ support,
                                                      const float* __restrict__ edge_val,
                                                      const int* __restrict__ edge_src,
                                                      const int* __restrict__ edge_dst,
                                                      float* __restrict__ out,
                                                      int n_edges) {
    const long gid = (long)blockIdx.x * blockDim.x + threadIdx.x;
    const int e = (int)(gid >> 4);
    if (e >= n_edges) return;
    const int fo = (int)(gid & 15) * 4;
    const int src   = edge_src[e];
    const int dst   = edge_dst[e];
    const float val = edge_val[e];
    const float4 s = *(const float4*)&support[(size_t)src * F_OUT + fo];
    float* o = &out[(size_t)dst * F_OUT + fo];
    atomicAdd(o + 0, val * s.x);
    atomicAdd(o + 1, val * s.y);
    atomicAdd(o + 2, val * s.z);
    atomicAdd(o + 3, val * s.w);
}

__global__ __launch_bounds__(256) void relu_kernel(float* __restrict__ out, int n4) {
    const int i = blockIdx.x * blockDim.x + threadIdx.x;
    if (i < n4) {
        float4 v = ((float4*)out)[i];
        v.x = fmaxf(v.x, 0.f); v.y = fmaxf(v.y, 0.f);
        v.z = fmaxf(v.z, 0.f); v.w = fmaxf(v.w, 0.f);
        ((float4*)out)[i] = v;
    }
}

extern "C" void kernel_launch(void* const* d_in, const int* in_sizes, int n_in,
                              void* d_out, int out_size, void* d_ws, size_t ws_size,
                              hipStream_t stream) {
    const float* x        = (const float*)d_in[0];
    const float* w        = (const float*)d_in[1];
    const float* edge_val = (const float*)d_in[2];
    const int*   edge_src = (const int*)d_in[3];
    const int*   edge_dst = (const int*)d_in[4];
    float* out = (float*)d_out;

    const int n_nodes = in_sizes[0] / F_IN;   // 100000
    const int n_edges = in_sizes[2];          // 1600000
    const int nb = (n_nodes + NPB - 1) >> NPB_SHIFT;   // 782 buckets
    const int S  = nb * NPART;                          // 6256 segments

    char* p = (char*)d_ws;
    float* support = (float*)p;  p += (size_t)n_nodes * F_OUT * sizeof(float);
    int2*  sorted  = (int2*)p;   p += (size_t)n_edges * sizeof(int2);
    int*   offsets = (int*)p;    p += (size_t)(S + 1) * sizeof(int);
    int*   cursors = (int*)p;    p += (size_t)S * CUR_STRIDE * sizeof(int);
    int*   g_hist  = (int*)p;    p += (size_t)S * sizeof(int);
    const size_t ws_needed = (size_t)(p - (char*)d_ws);

    const int gemm_blocks = (n_nodes + ROWS_PER_BLOCK - 1) / ROWS_PER_BLOCK;
    gemm_kernel<<<gemm_blocks, 256, 0, stream>>>(x, w, support, n_nodes);

    const bool ok = (ws_size >= ws_needed) && (nb <= BCAP) && (n_nodes < (1 << 20));
    if (ok) {
        hipMemsetAsync(g_hist, 0, (size_t)S * sizeof(int), stream);
        hist_kernel<<<256, 256, 0, stream>>>(edge_dst, g_hist, n_edges, nb);
        scan_kernel<<<1, 256, 0, stream>>>(g_hist, offsets, cursors, S);
        bscatter_kernel<<<1024, 256, 0, stream>>>(edge_val, edge_src, edge_dst,
                                                  cursors, sorted, n_edges);
        baccum_kernel<<<nb, 512, 0, stream>>>(support, sorted, offsets, out, n_nodes);
    } else {
        hipMemsetAsync(d_out, 0, (size_t)out_size * sizeof(float), stream);
        const long st = (long)n_edges * 16;
        scatter_kernel<<<(int)((st + 255) / 256), 256, 0, stream>>>(
            support, edge_val, edge_src, edge_dst, out, n_edges);
        const int n4o = out_size / 4;
        relu_kernel<<<(n4o + 255) / 256, 256, 0, stream>>>(out, n4o);
    }
}

// Round 7
// 233.286 us; speedup vs baseline: 3.9818x; 1.3222x over previous
//
#include <hip/hip_runtime.h>

#define F_IN 128
#define F_OUT 64
#define ROWS_PER_BLOCK 64

#define NPB 128          // nodes per bucket
#define NPB_SHIFT 7
#define BCAP 800         // max buckets (nb = 782)
#define ECAP 2560        // edges staged/sorted per LDS chunk in baccum
#define TILE 8192        // edges per block in bscatter multisplit
#define BSTH 1024        // bscatter threads

// ---------------------------------------------------------------------------
// Kernel 1: support = x @ weight   (fp32 vector-ALU GEMM; no fp32 MFMA on CDNA4)
// ---------------------------------------------------------------------------
__global__ __launch_bounds__(256) void gemm_kernel(const float* __restrict__ x,
                                                   const float* __restrict__ w,
                                                   float* __restrict__ support,
                                                   int n_nodes) {
    __shared__ float w_lds[F_IN * F_OUT];                 // 32 KB
    __shared__ float x_lds[ROWS_PER_BLOCK][F_IN + 1];     // ~33 KB

    const int tid = threadIdx.x;

    {
        const float4* w4 = (const float4*)w;
        float4* wl4 = (float4*)w_lds;
        #pragma unroll
        for (int i = tid; i < (F_IN * F_OUT) / 4; i += 256) wl4[i] = w4[i];
    }

    const int row0 = blockIdx.x * ROWS_PER_BLOCK;

    #pragma unroll
    for (int i = tid; i < ROWS_PER_BLOCK * (F_IN / 4); i += 256) {
        const int r   = i >> 5;
        const int k4  = i & 31;
        const int row = row0 + r;
        float4 v = make_float4(0.f, 0.f, 0.f, 0.f);
        if (row < n_nodes) v = ((const float4*)(x + (size_t)row * F_IN))[k4];
        x_lds[r][k4 * 4 + 0] = v.x;
        x_lds[r][k4 * 4 + 1] = v.y;
        x_lds[r][k4 * 4 + 2] = v.z;
        x_lds[r][k4 * 4 + 3] = v.w;
    }
    __syncthreads();

    const int tf = tid & 15;
    const int tr = tid >> 4;

    float acc[4][4] = {};
    #pragma unroll 4
    for (int k = 0; k < F_IN; ++k) {
        const float4 wv = *(const float4*)&w_lds[k * F_OUT + 4 * tf];
        const float x0 = x_lds[4 * tr + 0][k];
        const float x1 = x_lds[4 * tr + 1][k];
        const float x2 = x_lds[4 * tr + 2][k];
        const float x3 = x_lds[4 * tr + 3][k];
        acc[0][0] += x0 * wv.x; acc[0][1] += x0 * wv.y; acc[0][2] += x0 * wv.z; acc[0][3] += x0 * wv.w;
        acc[1][0] += x1 * wv.x; acc[1][1] += x1 * wv.y; acc[1][2] += x1 * wv.z; acc[1][3] += x1 * wv.w;
        acc[2][0] += x2 * wv.x; acc[2][1] += x2 * wv.y; acc[2][2] += x2 * wv.z; acc[2][3] += x2 * wv.w;
        acc[3][0] += x3 * wv.x; acc[3][1] += x3 * wv.y; acc[3][2] += x3 * wv.z; acc[3][3] += x3 * wv.w;
    }

    #pragma unroll
    for (int i = 0; i < 4; ++i) {
        const int row = row0 + 4 * tr + i;
        if (row < n_nodes) {
            float4 v = make_float4(acc[i][0], acc[i][1], acc[i][2], acc[i][3]);
            *(float4*)&support[(size_t)row * F_OUT + 4 * tf] = v;
        }
    }
}

// ---------------------------------------------------------------------------
// Kernel 2: per-bucket histogram of dst>>7 (LDS hist, one global add per bin).
// ---------------------------------------------------------------------------
__global__ __launch_bounds__(256) void hist_kernel(const int* __restrict__ edge_dst,
                                                   int* __restrict__ g_hist,
                                                   int n_edges, int nbuckets) {
    __shared__ int h[BCAP];
    for (int i = threadIdx.x; i < BCAP; i += 256) h[i] = 0;
    __syncthreads();

    const int n4 = n_edges >> 2;
    const int4* d4 = (const int4*)edge_dst;
    const int stride = gridDim.x * blockDim.x;
    for (int t = blockIdx.x * blockDim.x + threadIdx.x; t < n4; t += stride) {
        const int4 d = d4[t];
        atomicAdd(&h[d.x >> NPB_SHIFT], 1);
        atomicAdd(&h[d.y >> NPB_SHIFT], 1);
        atomicAdd(&h[d.z >> NPB_SHIFT], 1);
        atomicAdd(&h[d.w >> NPB_SHIFT], 1);
    }
    if (blockIdx.x == 0) {   // tail edges
        for (int e = (n4 << 2) + threadIdx.x; e < n_edges; e += 256)
            atomicAdd(&h[edge_dst[e] >> NPB_SHIFT], 1);
    }
    __syncthreads();
    for (int i = threadIdx.x; i < nbuckets; i += 256)
        if (h[i]) atomicAdd(&g_hist[i], h[i]);
}

// ---------------------------------------------------------------------------
// Kernel 3: single-block exclusive scan of nb (<=1024) bucket counts.
// Writes offsets[0..nb] and initializes cursors (mutated by bscatter).
// ---------------------------------------------------------------------------
__global__ __launch_bounds__(256) void scan_kernel(const int* __restrict__ g_hist,
                                                   int* __restrict__ offsets,
                                                   int* __restrict__ cursors,
                                                   int nb) {
    __shared__ int lds[256];
    const int tid = threadIdx.x;
    const int base = tid * 4;

    const int v0 = (base + 0 < nb) ? g_hist[base + 0] : 0;
    const int v1 = (base + 1 < nb) ? g_hist[base + 1] : 0;
    const int v2 = (base + 2 < nb) ? g_hist[base + 2] : 0;
    const int v3 = (base + 3 < nb) ? g_hist[base + 3] : 0;
    const int s1 = v0, s2 = s1 + v1, s3 = s2 + v2, s4 = s3 + v3;

    int t = s4;
    lds[tid] = t;
    __syncthreads();
    #pragma unroll
    for (int off = 1; off < 256; off <<= 1) {
        const int xv = (tid >= off) ? lds[tid - off] : 0;
        __syncthreads();
        t += xv;
        lds[tid] = t;
        __syncthreads();
    }
    const int excl = t - s4;
    const int e0 = excl, e1 = excl + s1, e2 = excl + s2, e3 = excl + s3;
    if (base + 0 < nb) { offsets[base + 0] = e0; cursors[base + 0] = e0; }
    if (base + 1 < nb) { offsets[base + 1] = e1; cursors[base + 1] = e1; }
    if (base + 2 < nb) { offsets[base + 2] = e2; cursors[base + 2] = e2; }
    if (base + 3 < nb) { offsets[base + 3] = e3; cursors[base + 3] = e3; }
    if (tid == 255) offsets[nb] = t;   // grand total = n_edges
}

// ---------------------------------------------------------------------------
// Kernel 4 (v3): block-level multisplit. One block owns a TILE of 8192 edges:
//   stage to LDS + 782-bin hist -> local scan -> ONE global atomicAdd per
//   nonempty bucket reserves a contiguous run -> rank edges -> write runs.
// Consecutive k in the write loop share a bucket for ~10.5 records (84 B),
// so lanes produce contiguous line-filling stores instead of random 8 B.
// sorted[pos].x = src | (dstLocal << 20); sorted[pos].y = val bits.
// ---------------------------------------------------------------------------
__global__ __launch_bounds__(BSTH) void bscatter_kernel(const float* __restrict__ edge_val,
                                                        const int* __restrict__ edge_src,
                                                        const int* __restrict__ edge_dst,
                                                        int* __restrict__ cursors,
                                                        int2* __restrict__ sorted,
                                                        int n_edges, int nb) {
    __shared__ int2 ebuf[TILE];                  // 64 KB
    __shared__ unsigned short bkt[TILE];         // 16 KB
    __shared__ unsigned short order[TILE];       // 16 KB
    __shared__ int h[BCAP];                      // 3.2 KB
    __shared__ int sbuf[BSTH];                   // 4 KB
    __shared__ int lcur[BCAP];                   // 3.2 KB
    __shared__ int delta[BCAP];                  // 3.2 KB

    const int tid = threadIdx.x;
    const int te  = blockIdx.x * TILE;
    const int cnt = min(TILE, n_edges - te);

    for (int i = tid; i < BCAP; i += BSTH) h[i] = 0;
    __syncthreads();

    // Stage + pack + bucket + LDS histogram (coalesced int4/float4 reads).
    const int cnt4 = cnt >> 2;
    const int4*   s4 = (const int4*)(edge_src + te);
    const int4*   d4 = (const int4*)(edge_dst + te);
    const float4* v4 = (const float4*)(edge_val + te);
    for (int t = tid; t < cnt4; t += BSTH) {
        const int4   s = s4[t];
        const int4   d = d4[t];
        const float4 v = v4[t];
        const int i = t << 2;
        int b;
        b = d.x >> NPB_SHIFT; bkt[i + 0] = (unsigned short)b; atomicAdd(&h[b], 1);
        ebuf[i + 0] = make_int2(s.x | ((d.x & (NPB - 1)) << 20), __float_as_int(v.x));
        b = d.y >> NPB_SHIFT; bkt[i + 1] = (unsigned short)b; atomicAdd(&h[b], 1);
        ebuf[i + 1] = make_int2(s.y | ((d.y & (NPB - 1)) << 20), __float_as_int(v.y));
        b = d.z >> NPB_SHIFT; bkt[i + 2] = (unsigned short)b; atomicAdd(&h[b], 1);
        ebuf[i + 2] = make_int2(s.z | ((d.z & (NPB - 1)) << 20), __float_as_int(v.z));
        b = d.w >> NPB_SHIFT; bkt[i + 3] = (unsigned short)b; atomicAdd(&h[b], 1);
        ebuf[i + 3] = make_int2(s.w | ((d.w & (NPB - 1)) << 20), __float_as_int(v.w));
    }
    for (int e = (cnt4 << 2) + tid; e < cnt; e += BSTH) {   // tail (<=3)
        const int dd = edge_dst[te + e];
        const int b = dd >> NPB_SHIFT;
        bkt[e] = (unsigned short)b;
        atomicAdd(&h[b], 1);
        ebuf[e] = make_int2(edge_src[te + e] | ((dd & (NPB - 1)) << 20),
                            __float_as_int(edge_val[te + e]));
    }
    __syncthreads();

    // Inclusive scan of bucket counts (1024-wide Hillis-Steele).
    sbuf[tid] = (tid < nb) ? h[tid] : 0;
    __syncthreads();
    #pragma unroll
    for (int off = 1; off < BSTH; off <<= 1) {
        const int v = (tid >= off) ? sbuf[tid - off] : 0;
        __syncthreads();
        sbuf[tid] += v;
        __syncthreads();
    }

    // Reserve global runs: one atomicAdd per nonempty bucket.
    if (tid < nb) {
        const int loff = sbuf[tid] - h[tid];      // exclusive local offset
        lcur[tid] = loff;
        if (h[tid] > 0) delta[tid] = atomicAdd(&cursors[tid], h[tid]) - loff;
    }
    __syncthreads();

    // Rank edges within the tile (order[rank] = edge index).
    for (int i = tid; i < cnt; i += BSTH) {
        const int r = atomicAdd(&lcur[bkt[i]], 1);
        order[r] = (unsigned short)i;
    }
    __syncthreads();

    // Write runs: consecutive k in one bucket -> consecutive global pos.
    for (int k = tid; k < cnt; k += BSTH) {
        const int i = order[k];
        sorted[delta[bkt[i]] + k] = ebuf[i];
    }
}

// ---------------------------------------------------------------------------
// Kernel 5: per-bucket counting sort in LDS + per-node REGISTER gather.
// ---------------------------------------------------------------------------
__global__ __launch_bounds__(512) void baccum_kernel(const float* __restrict__ support,
                                                     const int2* __restrict__ sorted,
                                                     const int* __restrict__ offsets,
                                                     float* __restrict__ out,
                                                     int n_nodes) {
    __shared__ int2 ebuf[ECAP];                    // 20 KB
    __shared__ unsigned short order[ECAP];         // 5 KB
    __shared__ int hist[NPB];
    __shared__ int scanbuf[NPB];
    __shared__ int node_off[NPB + 1];
    __shared__ int cursor[NPB];

    const int tid = threadIdx.x;
    const int bucket = blockIdx.x;
    const int beg = offsets[bucket];
    const int end = offsets[bucket + 1];

    const int g  = tid >> 4;        // group 0..31
    const int f4 = tid & 15;        // float4 feature index 0..15
    const float4* sup4 = (const float4*)support;

    float4 acc[4];
    #pragma unroll
    for (int j = 0; j < 4; ++j) acc[j] = make_float4(0.f, 0.f, 0.f, 0.f);

    for (int cb = beg; cb < end; cb += ECAP) {
        const int cnt = min(ECAP, end - cb);

        __syncthreads();                        // prev gather done / ebuf free
        if (tid < NPB) hist[tid] = 0;
        __syncthreads();

        // Stage + histogram.
        for (int i = tid; i < cnt; i += 512) {
            const int2 ev = sorted[cb + i];
            ebuf[i] = ev;
            atomicAdd(&hist[((unsigned)ev.x) >> 20], 1);
        }
        __syncthreads();

        // Inclusive scan of 128 bins.
        if (tid < NPB) scanbuf[tid] = hist[tid];
        __syncthreads();
        #pragma unroll
        for (int off = 1; off < NPB; off <<= 1) {
            int v = 0;
            if (tid < NPB && tid >= off) v = scanbuf[tid - off];
            __syncthreads();
            if (tid < NPB) scanbuf[tid] += v;
            __syncthreads();
        }
        if (tid < NPB) {
            node_off[tid + 1] = scanbuf[tid];
            cursor[tid] = scanbuf[tid] - hist[tid];   // exclusive start
            if (tid == 0) node_off[0] = 0;
        }
        __syncthreads();

        // Permutation: order[rank] = edge index within chunk.
        for (int i = tid; i < cnt; i += 512) {
            const int dl = ((unsigned)ebuf[i].x) >> 20;
            const int r = atomicAdd(&cursor[dl], 1);
            order[r] = (unsigned short)i;
        }
        __syncthreads();

        // Register gather: node j of this group = local node g + 32*j.
        #pragma unroll
        for (int j = 0; j < 4; ++j) {
            const int nl = g + 32 * j;
            int k = node_off[nl];
            const int ke = node_off[nl + 1];
            float4 a = acc[j];
            while (k + 4 <= ke) {
                int2 e0 = ebuf[order[k + 0]];
                int2 e1 = ebuf[order[k + 1]];
                int2 e2 = ebuf[order[k + 2]];
                int2 e3 = ebuf[order[k + 3]];
                const float4 s0 = sup4[(size_t)(e0.x & 0xFFFFF) * 16 + f4];
                const float4 s1 = sup4[(size_t)(e1.x & 0xFFFFF) * 16 + f4];
                const float4 s2 = sup4[(size_t)(e2.x & 0xFFFFF) * 16 + f4];
                const float4 s3 = sup4[(size_t)(e3.x & 0xFFFFF) * 16 + f4];
                const float v0 = __int_as_float(e0.y);
                const float v1 = __int_as_float(e1.y);
                const float v2 = __int_as_float(e2.y);
                const float v3 = __int_as_float(e3.y);
                a.x += v0 * s0.x; a.y += v0 * s0.y; a.z += v0 * s0.z; a.w += v0 * s0.w;
                a.x += v1 * s1.x; a.y += v1 * s1.y; a.z += v1 * s1.z; a.w += v1 * s1.w;
                a.x += v2 * s2.x; a.y += v2 * s2.y; a.z += v2 * s2.z; a.w += v2 * s2.w;
                a.x += v3 * s3.x; a.y += v3 * s3.y; a.z += v3 * s3.z; a.w += v3 * s3.w;
                k += 4;
            }
            for (; k < ke; ++k) {
                const int2 e0 = ebuf[order[k]];
                const float4 s0 = sup4[(size_t)(e0.x & 0xFFFFF) * 16 + f4];
                const float v0 = __int_as_float(e0.y);
                a.x += v0 * s0.x; a.y += v0 * s0.y; a.z += v0 * s0.z; a.w += v0 * s0.w;
            }
            acc[j] = a;
        }
    }

    // Writeout (also for empty buckets: zeros, ReLU(0)=0 matches segment_sum).
    const int base = bucket << NPB_SHIFT;
    #pragma unroll
    for (int j = 0; j < 4; ++j) {
        const int node = base + g + 32 * j;
        if (node < n_nodes) {
            float4 v = acc[j];
            v.x = fmaxf(v.x, 0.f); v.y = fmaxf(v.y, 0.f);
            v.z = fmaxf(v.z, 0.f); v.w = fmaxf(v.w, 0.f);
            ((float4*)out)[(size_t)node * 16 + f4] = v;
        }
    }
}

// ---------------------------------------------------------------------------
// Fallback (ws too small / shapes out of packing range): round-1 atomic path.
// ---------------------------------------------------------------------------
__global__ __launch_bounds__(256) void scatter_kernel(const float* __restrict__ support,
                                                      const float* __restrict__ edge_val,
                                                      const int* __restrict__ edge_src,
                                                      const int* __restrict__ edge_dst,
                                                      float* __restrict__ out,
                                                      int n_edges) {
    const long gid = (long)blockIdx.x * blockDim.x + threadIdx.x;
    const int e = (int)(gid >> 4);
    if (e >= n_edges) return;
    const int fo = (int)(gid & 15) * 4;
    const int src   = edge_src[e];
    const int dst   = edge_dst[e];
    const float val = edge_val[e];
    const float4 s = *(const float4*)&support[(size_t)src * F_OUT + fo];
    float* o = &out[(size_t)dst * F_OUT + fo];
    atomicAdd(o + 0, val * s.x);
    atomicAdd(o + 1, val * s.y);
    atomicAdd(o + 2, val * s.z);
    atomicAdd(o + 3, val * s.w);
}

__global__ __launch_bounds__(256) void relu_kernel(float* __restrict__ out, int n4) {
    const int i = blockIdx.x * blockDim.x + threadIdx.x;
    if (i < n4) {
        float4 v = ((float4*)out)[i];
        v.x = fmaxf(v.x, 0.f); v.y = fmaxf(v.y, 0.f);
        v.z = fmaxf(v.z, 0.f); v.w = fmaxf(v.w, 0.f);
        ((float4*)out)[i] = v;
    }
}

extern "C" void kernel_launch(void* const* d_in, const int* in_sizes, int n_in,
                              void* d_out, int out_size, void* d_ws, size_t ws_size,
                              hipStream_t stream) {
    const float* x        = (const float*)d_in[0];
    const float* w        = (const float*)d_in[1];
    const float* edge_val = (const float*)d_in[2];
    const int*   edge_src = (const int*)d_in[3];
    const int*   edge_dst = (const int*)d_in[4];
    float* out = (float*)d_out;

    const int n_nodes = in_sizes[0] / F_IN;   // 100000
    const int n_edges = in_sizes[2];          // 1600000
    const int nb = (n_nodes + NPB - 1) >> NPB_SHIFT;   // 782 buckets

    char* p = (char*)d_ws;
    float* support = (float*)p;  p += (size_t)n_nodes * F_OUT * sizeof(float);
    int2*  sorted  = (int2*)p;   p += (size_t)n_edges * sizeof(int2);
    int*   offsets = (int*)p;    p += (size_t)(nb + 1) * sizeof(int);
    int*   cursors = (int*)p;    p += (size_t)nb * sizeof(int);
    int*   g_hist  = (int*)p;    p += (size_t)nb * sizeof(int);
    const size_t ws_needed = (size_t)(p - (char*)d_ws);

    const int gemm_blocks = (n_nodes + ROWS_PER_BLOCK - 1) / ROWS_PER_BLOCK;
    gemm_kernel<<<gemm_blocks, 256, 0, stream>>>(x, w, support, n_nodes);

    const bool ok = (ws_size >= ws_needed) && (nb <= BCAP) && (n_nodes < (1 << 20));
    if (ok) {
        hipMemsetAsync(g_hist, 0, (size_t)nb * sizeof(int), stream);
        hist_kernel<<<256, 256, 0, stream>>>(edge_dst, g_hist, n_edges, nb);
        scan_kernel<<<1, 256, 0, stream>>>(g_hist, offsets, cursors, nb);
        const int sblocks = (n_edges + TILE - 1) / TILE;   // 196
        bscatter_kernel<<<sblocks, BSTH, 0, stream>>>(edge_val, edge_src, edge_dst,
                                                      cursors, sorted, n_edges, nb);
        baccum_kernel<<<nb, 512, 0, stream>>>(support, sorted, offsets, out, n_nodes);
    } else {
        hipMemsetAsync(d_out, 0, (size_t)out_size * sizeof(float), stream);
        const long st = (long)n_edges * 16;
        scatter_kernel<<<(int)((st + 255) / 256), 256, 0, stream>>>(
            support, edge_val, edge_src, edge_dst, out, n_edges);
        const int n4o = out_size / 4;
        relu_kernel<<<(n4o + 255) / 256, 256, 0, stream>>>(out, n4o);
    }
}